// Round 4
// baseline (146.609 us; speedup 1.0000x reference)
//
#include <hip/hip_runtime.h>
#include <hip/hip_bf16.h>
#include <cstdint>
#include <cstddef>

// B=4, C=128, L=4096, H=4 (hd=32), GROUPS=32, EPS=1e-5
// gn_stats (split stats: 2 blocks/group, partial sums; + weight cvt)
// -> MFMA qkv (gn finalize in-block; gn inline; Qt/Kt bf16 [l][32], Vb fp16 [32][l])
// -> MFMA flash attention v5: v4 structure + S-SPLIT x2 (grid 32x2x16 = 1024 blocks
//    = 4 blocks/CU = 100% wave-slot occupancy). No running max -> raw f32 O/l partials.
// -> combine kernel: ot = (Po0+Po1) * 1/(l0+l1), bf16 (memory-bound, ~3.5us)
// -> MFMA proj (+bias +raw-x residual), reads bf16 ot.
//
// ws layout (bytes):
//   wq_b  bf16 49,152    @ 0
//   wp_b  bf16 16,384    @ 98,304
//   bp_f  f32  128       @ 131,072
//   gpart f32x2 2,048    @ 131,584    [b][g][half] (s, ss)
//   Lg    f32  524,288   @ 139,264    [ss][bh][l]
//   ot    bf16 2,097,152 @ 8,388,608  (overlays dead Qt after attn)
//   Qt    bf16 2,097,152 @ 8,388,608  [b*H+h][l][32]
//   Kt    bf16 2,097,152 @ 12,582,912 [b*H+h][l][32]
//   Vb    fp16 2,097,152 @ 16,777,216 [b*H+h][32][l]
//   Po    f32  16,777,216 @ 20,971,520 [ss][b][l][128]
//   total 37,748,736

#define B_ 4
#define C_ 128
#define L_ 4096
#define H_ 4
#define HD_ 32
#define NG_ 32
#define CPG_ 4
#define EPS_ 1e-5f
#define QKSCALE_ 0.5050097650430367f  // 32^(-1/4) * sqrt(log2 e)

typedef __attribute__((ext_vector_type(8))) short bf16x8;
typedef __attribute__((ext_vector_type(8))) unsigned short u16x8;
typedef __attribute__((ext_vector_type(4))) float f32x4;
typedef __attribute__((ext_vector_type(16))) float f32x16;
typedef __attribute__((ext_vector_type(2))) _Float16 f16x2;
typedef __attribute__((ext_vector_type(4))) _Float16 f16x4;
typedef __attribute__((ext_vector_type(8))) _Float16 f16x8;
typedef __attribute__((ext_vector_type(2))) unsigned int u32x2;
typedef __attribute__((ext_vector_type(4))) unsigned int u32x4;

#if __has_builtin(__builtin_amdgcn_exp2f)
#define EXP2F(x) __builtin_amdgcn_exp2f(x)
#else
#define EXP2F(x) exp2f(x)
#endif

__device__ __forceinline__ float bu2f(unsigned short u) {
  return __builtin_bit_cast(float, (unsigned int)(((unsigned int)u) << 16));
}
__device__ __forceinline__ unsigned short f2bu(float f) {
  unsigned int u = __builtin_bit_cast(unsigned int, f);
  unsigned int r = (u + 0x7fffu + ((u >> 16) & 1u)) >> 16;  // RNE
  return (unsigned short)r;
}
__device__ __forceinline__ float4 u42f4(ushort4 u) {
  return make_float4(bu2f(u.x), bu2f(u.y), bu2f(u.z), bu2f(u.w));
}
__device__ __forceinline__ unsigned int pkbf(float a, float b) {
  return (unsigned int)f2bu(a) | ((unsigned int)f2bu(b) << 16);
}
__device__ __forceinline__ f16x2 pkhf2(float a, float b) {
#if __has_builtin(__builtin_amdgcn_cvt_pkrtz)
  return __builtin_bit_cast(f16x2, __builtin_amdgcn_cvt_pkrtz(a, b));
#else
  f16x2 r;
  r[0] = (_Float16)a;
  r[1] = (_Float16)b;
  return r;
#endif
}
__device__ __forceinline__ unsigned int pkhf(float a, float b) {
  return __builtin_bit_cast(unsigned int, pkhf2(a, b));
}

// async global->LDS DMA, 16B per lane. LDS dest must be wave-uniform base + lane*16.
__device__ __forceinline__ void gload16(const void* g, void* l) {
  __builtin_amdgcn_global_load_lds(
      (const __attribute__((address_space(1))) unsigned int*)g,
      (__attribute__((address_space(3))) unsigned int*)l, 16, 0, 0);
}

// fp32-vs-bf16 detection via wave-0 ballot — proven R9.
__device__ __forceinline__ bool detect_fast(const ushort* x) {
  __shared__ int flag_s;
  int t = threadIdx.x;
  if (t < 64) {
    int e = (x[t] >> 7) & 0xFF;
    unsigned long long m = __ballot((e < 64) || (e > 192));
    if (t == 0) flag_s = (__popcll(m) > 4) ? 1 : 0;
  }
  __syncthreads();
  return flag_s != 0;
}

__device__ __forceinline__ float4 ldx4(const void* x, size_t idx, bool f32) {
  if (f32) return *((const float4*)x + (idx >> 2));
  ushort4 u = *((const ushort4*)x + (idx >> 2));
  return u42f4(u);
}

// ---------------------------------------------------------------- GN stats + weight cvt
// Stats split: 2 blocks per (b,g), each reduces a 2048-L half of all 4 channels and
// stores a raw partial (s, ss) — no atomics, finalized inside qkv.
__global__ __launch_bounds__(256) void gn_stats(const void* __restrict__ x,
                                                const void* __restrict__ wq,
                                                const void* __restrict__ wp,
                                                const void* __restrict__ bp,
                                                ushort* __restrict__ wq_b,
                                                ushort* __restrict__ wp_b,
                                                float* __restrict__ bp_f,
                                                float2* __restrict__ gpart) {
  bool f32 = detect_fast((const ushort*)x);
  int blk = blockIdx.x;
  int t = threadIdx.x;

  if (blk >= 256) {
    int i0 = ((blk - 256) * 256 + t) * 8;
#pragma unroll
    for (int k = 0; k < 8; ++k) {
      int i = i0 + k;
      if (i >= 65664) break;
      if (i < 49152) {
        wq_b[i] = f32 ? f2bu(((const float*)wq)[i]) : ((const ushort*)wq)[i];
      } else if (i < 65536) {
        int off = i - 49152;
        wp_b[off] = f32 ? f2bu(((const float*)wp)[off]) : ((const ushort*)wp)[off];
      } else {
        int off = i - 65536;
        bp_f[off] = f32 ? ((const float*)bp)[off] : bu2f(((const ushort*)bp)[off]);
      }
    }
    return;
  }

  int b = blk >> 6, rem = blk & 63;
  int g = rem >> 1, half = rem & 1;
  size_t base = ((size_t)b * C_ + (size_t)g * CPG_) * L_ + (size_t)half * 2048;

  float s = 0.f, ss = 0.f;
#pragma unroll
  for (int cc = 0; cc < 4; ++cc) {
#pragma unroll
    for (int i = 0; i < 2; ++i) {
      size_t e = base + (size_t)cc * L_ + i * 1024 + t * 4;
      float4 f = ldx4(x, e, f32);
      s += f.x + f.y + f.z + f.w;
      ss += f.x * f.x + f.y * f.y + f.z * f.z + f.w * f.w;
    }
  }
#pragma unroll
  for (int m = 32; m >= 1; m >>= 1) {
    s += __shfl_xor(s, m, 64);
    ss += __shfl_xor(ss, m, 64);
  }
  __shared__ float red[4][2];
  int wv = t >> 6;
  if ((t & 63) == 0) { red[wv][0] = s; red[wv][1] = ss; }
  __syncthreads();
  if (t == 0) {
    float ts = red[0][0] + red[1][0] + red[2][0] + red[3][0];
    float tss = red[0][1] + red[1][1] + red[2][1] + red[3][1];
    gpart[(b * 32 + g) * 2 + half] = make_float2(ts, tss);
  }
}

// ---------------------------------------------------------------- QKV GEMM (MFMA, gn inline)
// GN finalize in-block from gpart partials (cheap, redundant per block).
__global__ __launch_bounds__(256) void qkv_kernel(const ushort* __restrict__ wq_b,
                                                  const void* __restrict__ x,
                                                  const float2* __restrict__ gpart,
                                                  const void* __restrict__ gm,
                                                  const void* __restrict__ bt,
                                                  ushort* __restrict__ Qt,
                                                  ushort* __restrict__ Kt,
                                                  ushort* __restrict__ Vb) {
  bool f32 = detect_fast((const ushort*)x);
  __shared__ alignas(16) ushort Hs[64][136];
  __shared__ alignas(16) float Ls[64][69];
  __shared__ float2 abs_s[128];

  int lx = blockIdx.x, oz = blockIdx.y, b = blockIdx.z;
  int t = threadIdx.x;
  int w = t >> 6, lane = t & 63, l16 = lane & 15, q = lane >> 4, q8 = q * 8;

  if (t < 64) {
#pragma unroll
    for (int k = 0; k < 2; ++k) {
      int c = 2 * t + k;
      int g = c >> 2;
      float2 p0 = gpart[(b * 32 + g) * 2];
      float2 p1 = gpart[(b * 32 + g) * 2 + 1];
      float mu = (p0.x + p1.x) * (1.0f / 16384.0f);
      float var = (p0.y + p1.y) * (1.0f / 16384.0f) - mu * mu;
      float rs = rsqrtf(var + EPS_);
      float ga = f32 ? ((const float*)gm)[c] : bu2f(((const ushort*)gm)[c]);
      float be = f32 ? ((const float*)bt)[c] : bu2f(((const ushort*)bt)[c]);
      abs_s[c] = make_float2(ga * rs, be - mu * ga * rs);
    }
  }
  __syncthreads();

  {
    int u = t & 63, lh = (t >> 6) * 16;
    int c0 = 2 * u;
    float2 ab0 = abs_s[c0];
    float2 ab1 = abs_s[c0 + 1];
    size_t xo = ((size_t)b * C_ + c0) * L_ + (size_t)lx * 64 + lh;
#pragma unroll
    for (int j = 0; j < 4; ++j) {
      float4 f0 = ldx4(x, xo + j * 4, f32);
      float4 f1 = ldx4(x, xo + L_ + j * 4, f32);
      float n0[4] = {f0.x * ab0.x + ab0.y, f0.y * ab0.x + ab0.y,
                     f0.z * ab0.x + ab0.y, f0.w * ab0.x + ab0.y};
      float n1[4] = {f1.x * ab1.x + ab1.y, f1.y * ab1.x + ab1.y,
                     f1.z * ab1.x + ab1.y, f1.w * ab1.x + ab1.y};
#pragma unroll
      for (int k = 0; k < 4; ++k)
        *(unsigned int*)&Hs[lh + j * 4 + k][c0] = pkbf(n0[k], n1[k]);
    }
  }
  __syncthreads();

  for (int j = 0; j < 2; ++j) {
    int oy = oz * 2 + j;
    const ushort* wg = wq_b + (size_t)(oy * 64 + w * 16 + l16) * C_;

    f32x4 acc[4] = {{0.f, 0.f, 0.f, 0.f}, {0.f, 0.f, 0.f, 0.f},
                    {0.f, 0.f, 0.f, 0.f}, {0.f, 0.f, 0.f, 0.f}};
#pragma unroll
    for (int kc = 0; kc < 4; ++kc) {
      bf16x8 aw = *(const bf16x8*)(wg + kc * 32 + q8);
#pragma unroll
      for (int nb = 0; nb < 4; ++nb) {
        bf16x8 bh = *(const bf16x8*)&Hs[nb * 16 + l16][kc * 32 + q8];
        acc[nb] = __builtin_amdgcn_mfma_f32_16x16x32_bf16(aw, bh, acc[nb], 0, 0, 0);
      }
    }
    __syncthreads();
#pragma unroll
    for (int nb = 0; nb < 4; ++nb)
#pragma unroll
      for (int r = 0; r < 4; ++r)
        Ls[nb * 16 + l16][w * 16 + 4 * q + r] = acc[nb][r];
    __syncthreads();

#pragma unroll
    for (int hhalf = 0; hhalf < 2; ++hhalf) {
      int hh = oy * 2 + hhalf;
      int type = hh % 3, head = hh / 3;
      size_t bh = (size_t)b * H_ + head;
      if (type == 2) {
        int c_loc = t >> 3, l8 = (t & 7) * 8;
        float v[8];
#pragma unroll
        for (int jj = 0; jj < 8; ++jj) v[jj] = Ls[l8 + jj][hhalf * 32 + c_loc];
        uint4 u;
        u.x = pkhf(v[0], v[1]);
        u.y = pkhf(v[2], v[3]);
        u.z = pkhf(v[4], v[5]);
        u.w = pkhf(v[6], v[7]);
        *(uint4*)(Vb + (bh * 32 + c_loc) * L_ + (size_t)lx * 64 + l8) = u;
      } else {
        ushort* dst = type ? Kt : Qt;
        int l = t >> 2, seg = (t & 3) * 8;
        const float* src = &Ls[l][hhalf * 32 + seg];
        uint4 u;
        u.x = pkbf(src[0] * QKSCALE_, src[1] * QKSCALE_);
        u.y = pkbf(src[2] * QKSCALE_, src[3] * QKSCALE_);
        u.z = pkbf(src[4] * QKSCALE_, src[5] * QKSCALE_);
        u.w = pkbf(src[6] * QKSCALE_, src[7] * QKSCALE_);
        *(uint4*)(dst + ((bh * L_) + lx * 64 + l) * 32 + seg) = u;
      }
    }
  }
}

// ---------------------------------------------------------------- MFMA flash attention v5
// v4 wave mapping (8 waves = 4 q-tiles x 2 s-halves) + s-split across grid.y (2048 s,
// 16 iters). No running max -> raw f32 partials: Po[ss][b][l][128], Lg[ss][bh][l].
__global__ __launch_bounds__(512, 8) void attn_kernel(const ushort* __restrict__ Qt,
                                                      const ushort* __restrict__ Kt,
                                                      const ushort* __restrict__ Vb,
                                                      float* __restrict__ Po,
                                                      float* __restrict__ Lg) {
  // [0,16384): K 2 bufs x 8192B ; [16384,32768): V 2 bufs x 8192B
  // epilogue overlay: Osh [8][32][33] f32 = 33792B ; Lp [4][128] f32 @ 33792
  __shared__ alignas(16) char smem[35840];

  int t = threadIdx.x;
  int w = t >> 6, lane = t & 63, l31 = lane & 31, hi = lane >> 5;
  int qt = w & 3, sh = w >> 2;
  int tq0 = blockIdx.x * 128;
  int ss = blockIdx.y;
  int bh = blockIdx.z;
  int b = bh >> 2, head = bh & 3;
  const ushort* Qg = Qt + ((size_t)bh * L_ + tq0) * 32;
  const ushort* Kg = Kt + ((size_t)bh * L_ + (size_t)ss * 2048) * 32;
  const ushort* Vg = Vb + (size_t)bh * 32 * L_ + (size_t)ss * 2048;

  // staging sources (pre-swizzled so linear DMA dest yields swizzled LDS)
  int rd = t >> 2, pd = t & 3;
  int kcsem = (pd - rd) & 3;
  const ushort* ksrc = Kg + (size_t)rd * 32 + kcsem * 8;
  int vr = t >> 4, vp = t & 15;
  int vcsem = (vp & 8) | ((vp & 7) ^ (vr & 7));
  const ushort* vsrc = Vg + (size_t)vr * L_ + vcsem * 8;

  char* kb0 = smem;
  char* kb1 = smem + 8192;
  char* vb0 = smem + 16384;
  char* vb1 = smem + 24576;

  // Q fragments (B operand): lane holds Q[q=qt*32+l31][k = 8*hi + j] (+16 for second K-half)
  const ushort* qbase = Qg + (size_t)(qt * 32 + l31) * 32;
  bf16x8 qB0 = *(const bf16x8*)(qbase + 8 * hi);
  bf16x8 qB1 = *(const bf16x8*)(qbase + 16 + 8 * hi);

  const f16x2 one2 = {(_Float16)1.0f, (_Float16)1.0f};

  // prologue: DMA tile 0 into buf A
  gload16(ksrc, kb0 + (size_t)t * 16);
  gload16(vsrc, vb0 + (size_t)t * 16);
  ksrc += 4096;
  vsrc += 128;
  __syncthreads();

  f32x16 aO = {0.f};
  float lsum = 0.f;

  int flip = 0;
  for (int it = 0; it < 16; ++it) {
    if (it < 15) {
      gload16(ksrc, (flip ? kb0 : kb1) + (size_t)t * 16);
      gload16(vsrc, (flip ? vb0 : vb1) + (size_t)t * 16);
      ksrc += 4096;
      vsrc += 128;
    }
    const ushort* kc = (const ushort*)(flip ? kb1 : kb0);
    const ushort* vc = (const ushort*)(flip ? vb1 : vb0);

#pragma unroll
    for (int st = 0; st < 2; ++st) {
      int s0 = 64 * sh + 32 * st;
      const ushort* krow = kc + (size_t)(s0 + l31) * 32;
      bf16x8 aK0 = *(const bf16x8*)(krow + ((hi + l31) & 3) * 8);
      bf16x8 aK1 = *(const bf16x8*)(krow + ((2 + hi + l31) & 3) * 8);
      f32x16 zz = {0.f};
      f32x16 sf;
      __builtin_amdgcn_s_setprio(1);
      sf = __builtin_amdgcn_mfma_f32_32x32x16_bf16(aK0, qB0, zz, 0, 0, 0);
      sf = __builtin_amdgcn_mfma_f32_32x32x16_bf16(aK1, qB1, sf, 0, 0, 0);
      __builtin_amdgcn_s_setprio(0);

#pragma unroll
      for (int sb = 0; sb < 2; ++sb) {
        int sblk = 4 * sh + 2 * st + sb;
        // V fragment (A operand): V[c=l31][s = sblk*16 + 8*hi + j]
        int kci = 2 * sblk + hi;
        int vpos = (kci & 8) | ((kci & 7) ^ (l31 & 7));
        f16x8 vf = *(const f16x8*)(vc + (size_t)l31 * 128 + vpos * 8);

        float p0 = EXP2F(sf[8 * sb + 0]);
        float p1 = EXP2F(sf[8 * sb + 1]);
        float p2 = EXP2F(sf[8 * sb + 2]);
        float p3 = EXP2F(sf[8 * sb + 3]);
        float p4 = EXP2F(sf[8 * sb + 4]);
        float p5 = EXP2F(sf[8 * sb + 5]);
        float p6 = EXP2F(sf[8 * sb + 6]);
        float p7 = EXP2F(sf[8 * sb + 7]);
        f16x2 cA0 = pkhf2(p0, p1), cA1 = pkhf2(p2, p3);
        f16x2 cB0 = pkhf2(p4, p5), cB1 = pkhf2(p6, p7);
        lsum = __builtin_amdgcn_fdot2(cA0, one2, lsum, false);
        lsum = __builtin_amdgcn_fdot2(cA1, one2, lsum, false);
        lsum = __builtin_amdgcn_fdot2(cB0, one2, lsum, false);
        lsum = __builtin_amdgcn_fdot2(cB1, one2, lsum, false);

        // B-fragment repack: (w0,w2) = swap(qA.x, qB.x); (w1,w3) = swap(qA.y, qB.y)
        u32x2 r0 = __builtin_amdgcn_permlane32_swap(
            __builtin_bit_cast(unsigned int, cA0),
            __builtin_bit_cast(unsigned int, cB0), false, false);
        u32x2 r1 = __builtin_amdgcn_permlane32_swap(
            __builtin_bit_cast(unsigned int, cA1),
            __builtin_bit_cast(unsigned int, cB1), false, false);
        u32x4 pw = {r0.x, r1.x, r0.y, r1.y};
        f16x8 pf = __builtin_bit_cast(f16x8, pw);

        __builtin_amdgcn_s_setprio(1);
        aO = __builtin_amdgcn_mfma_f32_32x32x16_f16(vf, pf, aO, 0, 0, 0);
        __builtin_amdgcn_s_setprio(0);
      }
    }
    __syncthreads();
    flip ^= 1;
  }

  // ---- epilogue: write partials (padded rows: bank = (l31 + c) % 32, conflict-free)
  float* Osh = (float*)smem;                // [slot=sh*4+qt][q=32][c=33pad]
  float* Lp = (float*)(smem + 33792);       // [sh*2+hi][128]
  {
    float* ob = Osh + (size_t)(sh * 4 + qt) * (32 * 33) + (size_t)l31 * 33;
#pragma unroll
    for (int reg = 0; reg < 16; ++reg) {
      int R = (reg & 3) + 8 * (reg >> 2) + 4 * hi;
      ob[R] = aO[reg];
    }
    Lp[(sh * 2 + hi) * 128 + qt * 32 + l31] = lsum;
  }
  __syncthreads();

  // combine s-halves + hi-halves (raw, unnormalized), coalesced f32 store
  {
    int qloc = t >> 2, c0 = (t & 3) * 8;
    int qt2 = qloc >> 5, q31 = qloc & 31;
    float lt = Lp[qloc] + Lp[128 + qloc] + Lp[256 + qloc] + Lp[384 + qloc];
    const float* o0 = Osh + (size_t)qt2 * (32 * 33) + (size_t)q31 * 33 + c0;
    const float* o1 = o0 + 4 * (32 * 33);
    float o[8];
#pragma unroll
    for (int jj = 0; jj < 8; ++jj) o[jj] = o0[jj] + o1[jj];
    float* dst = Po + (size_t)ss * ((size_t)B_ * L_ * C_) +
                 ((size_t)b * L_ + tq0 + qloc) * C_ + head * 32 + c0;
    *(float4*)dst = make_float4(o[0], o[1], o[2], o[3]);
    *(float4*)(dst + 4) = make_float4(o[4], o[5], o[6], o[7]);
    if ((t & 3) == 0) Lg[((size_t)ss * 16 + bh) * L_ + tq0 + qloc] = lt;
  }
}

// ---------------------------------------------------------------- combine partials -> bf16 ot
__global__ __launch_bounds__(256) void combine_kernel(const float* __restrict__ Po,
                                                      const float* __restrict__ Lg,
                                                      ushort* __restrict__ ot) {
  int tl = blockIdx.x * 256 + threadIdx.x;
  int row = tl >> 4;            // b*L + l
  int c0 = (tl & 15) * 8;
  int head = c0 >> 5;
  int b = row >> 12, l = row & 4095;
  const size_t HALF = (size_t)B_ * L_ * C_;
  const float* p0 = Po + (size_t)row * C_ + c0;
  const float* p1 = p0 + HALF;
  float lv = Lg[(size_t)(b * 4 + head) * L_ + l] +
             Lg[(size_t)(16 + b * 4 + head) * L_ + l];
  float inv = 1.0f / lv;
  float4 a0 = *(const float4*)p0;
  float4 a1 = *(const float4*)(p0 + 4);
  float4 b0 = *(const float4*)p1;
  float4 b1 = *(const float4*)(p1 + 4);
  uint4 u;
  u.x = pkbf((a0.x + b0.x) * inv, (a0.y + b0.y) * inv);
  u.y = pkbf((a0.z + b0.z) * inv, (a0.w + b0.w) * inv);
  u.z = pkbf((a1.x + b1.x) * inv, (a1.y + b1.y) * inv);
  u.w = pkbf((a1.z + b1.z) * inv, (a1.w + b1.w) * inv);
  *(uint4*)(ot + (size_t)row * C_ + c0) = u;
}

// ---------------------------------------------------------------- Proj + bias + residual
__global__ __launch_bounds__(256) void proj_kernel(const ushort* __restrict__ wp_b,
                                                   const float* __restrict__ bias,
                                                   const void* __restrict__ x,
                                                   const ushort* __restrict__ ot,
                                                   void* __restrict__ out) {
  bool f32 = detect_fast((const ushort*)x);
  __shared__ alignas(16) float Ls[64][37];

  int lx = blockIdx.x, oy = blockIdx.y, b = blockIdx.z;
  int t = threadIdx.x;
  int w = t >> 6, lane = t & 63, l16 = lane & 15, q = lane >> 4, q8 = q * 8;

  const ushort* wg = wp_b + (size_t)(oy * 64 + w * 16 + l16) * C_;
  const ushort* og = ot + ((size_t)b * L_ + (size_t)lx * 32) * C_;

  f32x4 acc[2] = {{0.f, 0.f, 0.f, 0.f}, {0.f, 0.f, 0.f, 0.f}};
#pragma unroll
  for (int kc = 0; kc < 4; ++kc) {
    bf16x8 aw = *(const bf16x8*)(wg + kc * 32 + q8);
#pragma unroll
    for (int nb = 0; nb < 2; ++nb) {
      bf16x8 bo = *(const bf16x8*)(og + (size_t)(nb * 16 + l16) * C_ + kc * 32 + q8);
      acc[nb] = __builtin_amdgcn_mfma_f32_16x16x32_bf16(aw, bo, acc[nb], 0, 0, 0);
    }
  }
#pragma unroll
  for (int nb = 0; nb < 2; ++nb)
#pragma unroll
    for (int r = 0; r < 4; ++r)
      Ls[w * 16 + 4 * q + r][nb * 16 + l16] = acc[nb][r];
  __syncthreads();

  {
    int o_loc = t >> 2, ls0 = (t & 3) * 8;
    float bv = bias[oy * 64 + o_loc];
    size_t off = ((size_t)b * C_ + oy * 64 + o_loc) * L_ + (size_t)lx * 32 + ls0;
#pragma unroll
    for (int jj = 0; jj < 2; ++jj) {
      float4 xf = ldx4(x, off + jj * 4, f32);
      const float* sp = &Ls[o_loc][ls0 + jj * 4];
      float4 r = make_float4(sp[0] + bv + xf.x, sp[1] + bv + xf.y,
                             sp[2] + bv + xf.z, sp[3] + bv + xf.w);
      if (f32) {
        *(float4*)((float*)out + off + jj * 4) = r;
      } else {
        *(ushort4*)((ushort*)out + off + jj * 4) =
            make_ushort4(f2bu(r.x), f2bu(r.y), f2bu(r.z), f2bu(r.w));
      }
    }
  }
}

// ---------------------------------------------------------------- launch
extern "C" void kernel_launch(void* const* d_in, const int* in_sizes, int n_in,
                              void* d_out, int out_size, void* d_ws, size_t ws_size,
                              hipStream_t stream) {
  const void* x      = d_in[0];
  const void* w_qkv  = d_in[1];
  const void* w_proj = d_in[2];
  const void* b_proj = d_in[3];
  const void* gamma  = d_in[4];
  const void* beta   = d_in[5];

  char* wsb = (char*)d_ws;
  ushort* wq_b  = (ushort*)(wsb + 0);
  ushort* wp_b  = (ushort*)(wsb + 98304);
  float*  bp_f  = (float*)(wsb + 131072);
  float2* gpart = (float2*)(wsb + 131584);
  float*  Lg    = (float*)(wsb + 139264);
  ushort* Qt    = (ushort*)(wsb + 8388608);
  ushort* ot    = (ushort*)(wsb + 8388608);   // overlays Qt (dead after attn)
  ushort* Kt    = (ushort*)(wsb + 12582912);
  ushort* Vb    = (ushort*)(wsb + 16777216);  // fp16
  float*  Po    = (float*)(wsb + 20971520);   // 2 x B*L*C f32

  gn_stats<<<dim3(289), dim3(256), 0, stream>>>(x, w_qkv, w_proj, b_proj,
                                                wq_b, wp_b, bp_f, gpart);
  qkv_kernel<<<dim3(L_ / 64, 3, B_), dim3(256), 0, stream>>>(wq_b, x, gpart, gamma, beta,
                                                             Qt, Kt, Vb);
  attn_kernel<<<dim3(L_ / 128, 2, B_ * H_), dim3(512), 0, stream>>>(Qt, Kt, Vb, Po, Lg);
  combine_kernel<<<dim3(1024), dim3(256), 0, stream>>>(Po, Lg, ot);
  proj_kernel<<<dim3(L_ / 32, C_ / 64, B_), dim3(256), 0, stream>>>(wp_b, bp_f, x, ot, d_out);
}

// Round 5
// 140.471 us; speedup vs baseline: 1.0437x; 1.0437x over previous
//
#include <hip/hip_runtime.h>
#include <hip/hip_bf16.h>
#include <cstdint>
#include <cstddef>

// B=4, C=128, L=4096, H=4 (hd=32), GROUPS=32, EPS=1e-5
// gn_stats (split stats: 2 blocks/group, partial sums; + weight cvt)
// -> MFMA qkv (gn finalize in-block; gn inline; Qt/Kt bf16 [l][32], Vb fp16 [32][l])
// -> MFMA flash attention v6 (this round): R3(v4) wave mapping (8 waves = 4 q-tiles
//    x 2 s-halves, 128-q block, 128 s/iter, full 4096-s sweep) + COUNTED-VMCNT
//    PIPELINE: 4-slot LDS ring (K 4x8KB + V 4x8KB = 64KB), 3 tiles in flight,
//    s_waitcnt vmcnt(4) (never 0 mid-loop) + raw s_barrier. Removes the per-iter
//    full DMA drain that __syncthreads() forces.
// -> MFMA proj (+bias +raw-x residual), reads bf16 ot.
//
// ws layout (bytes):
//   wq_b  bf16 49,152   @ 0
//   wp_b  bf16 16,384   @ 98,304
//   bp_f  f32  128      @ 131,072
//   gpart f32x2 2,048   @ 131,584   [b][g][half] (s, ss)
//   Qt    bf16 2,097,152 @ 8,388,608   [b*H+h][l][32]
//   Kt    bf16 2,097,152 @ 12,582,912  [b*H+h][l][32]
//   Vb    fp16 2,097,152 @ 16,777,216  [b*H+h][32][l]
//   ot    bf16 2,097,152 @ 20,971,520  [b][l][128]

#define B_ 4
#define C_ 128
#define L_ 4096
#define H_ 4
#define HD_ 32
#define NG_ 32
#define CPG_ 4
#define EPS_ 1e-5f
#define QKSCALE_ 0.5050097650430367f  // 32^(-1/4) * sqrt(log2 e)

typedef __attribute__((ext_vector_type(8))) short bf16x8;
typedef __attribute__((ext_vector_type(8))) unsigned short u16x8;
typedef __attribute__((ext_vector_type(4))) float f32x4;
typedef __attribute__((ext_vector_type(16))) float f32x16;
typedef __attribute__((ext_vector_type(2))) _Float16 f16x2;
typedef __attribute__((ext_vector_type(4))) _Float16 f16x4;
typedef __attribute__((ext_vector_type(8))) _Float16 f16x8;
typedef __attribute__((ext_vector_type(2))) unsigned int u32x2;
typedef __attribute__((ext_vector_type(4))) unsigned int u32x4;

#if __has_builtin(__builtin_amdgcn_exp2f)
#define EXP2F(x) __builtin_amdgcn_exp2f(x)
#else
#define EXP2F(x) exp2f(x)
#endif

__device__ __forceinline__ float bu2f(unsigned short u) {
  return __builtin_bit_cast(float, (unsigned int)(((unsigned int)u) << 16));
}
__device__ __forceinline__ unsigned short f2bu(float f) {
  unsigned int u = __builtin_bit_cast(unsigned int, f);
  unsigned int r = (u + 0x7fffu + ((u >> 16) & 1u)) >> 16;  // RNE
  return (unsigned short)r;
}
__device__ __forceinline__ float4 u42f4(ushort4 u) {
  return make_float4(bu2f(u.x), bu2f(u.y), bu2f(u.z), bu2f(u.w));
}
__device__ __forceinline__ unsigned int pkbf(float a, float b) {
  return (unsigned int)f2bu(a) | ((unsigned int)f2bu(b) << 16);
}
__device__ __forceinline__ f16x2 pkhf2(float a, float b) {
#if __has_builtin(__builtin_amdgcn_cvt_pkrtz)
  return __builtin_bit_cast(f16x2, __builtin_amdgcn_cvt_pkrtz(a, b));
#else
  f16x2 r;
  r[0] = (_Float16)a;
  r[1] = (_Float16)b;
  return r;
#endif
}
__device__ __forceinline__ unsigned int pkhf(float a, float b) {
  return __builtin_bit_cast(unsigned int, pkhf2(a, b));
}

// async global->LDS DMA, 16B per lane. LDS dest must be wave-uniform base + lane*16.
__device__ __forceinline__ void gload16(const void* g, void* l) {
  __builtin_amdgcn_global_load_lds(
      (const __attribute__((address_space(1))) unsigned int*)g,
      (__attribute__((address_space(3))) unsigned int*)l, 16, 0, 0);
}

// fp32-vs-bf16 detection via wave-0 ballot — proven R9.
__device__ __forceinline__ bool detect_fast(const ushort* x) {
  __shared__ int flag_s;
  int t = threadIdx.x;
  if (t < 64) {
    int e = (x[t] >> 7) & 0xFF;
    unsigned long long m = __ballot((e < 64) || (e > 192));
    if (t == 0) flag_s = (__popcll(m) > 4) ? 1 : 0;
  }
  __syncthreads();
  return flag_s != 0;
}

__device__ __forceinline__ float4 ldx4(const void* x, size_t idx, bool f32) {
  if (f32) return *((const float4*)x + (idx >> 2));
  ushort4 u = *((const ushort4*)x + (idx >> 2));
  return u42f4(u);
}

// ---------------------------------------------------------------- GN stats + weight cvt
// Stats split: 2 blocks per (b,g), each reduces a 2048-L half of all 4 channels and
// stores a raw partial (s, ss) — no atomics, finalized inside qkv.
__global__ __launch_bounds__(256) void gn_stats(const void* __restrict__ x,
                                                const void* __restrict__ wq,
                                                const void* __restrict__ wp,
                                                const void* __restrict__ bp,
                                                ushort* __restrict__ wq_b,
                                                ushort* __restrict__ wp_b,
                                                float* __restrict__ bp_f,
                                                float2* __restrict__ gpart) {
  bool f32 = detect_fast((const ushort*)x);
  int blk = blockIdx.x;
  int t = threadIdx.x;

  if (blk >= 256) {
    int i0 = ((blk - 256) * 256 + t) * 8;
#pragma unroll
    for (int k = 0; k < 8; ++k) {
      int i = i0 + k;
      if (i >= 65664) break;
      if (i < 49152) {
        wq_b[i] = f32 ? f2bu(((const float*)wq)[i]) : ((const ushort*)wq)[i];
      } else if (i < 65536) {
        int off = i - 49152;
        wp_b[off] = f32 ? f2bu(((const float*)wp)[off]) : ((const ushort*)wp)[off];
      } else {
        int off = i - 65536;
        bp_f[off] = f32 ? ((const float*)bp)[off] : bu2f(((const ushort*)bp)[off]);
      }
    }
    return;
  }

  int b = blk >> 6, rem = blk & 63;
  int g = rem >> 1, half = rem & 1;
  size_t base = ((size_t)b * C_ + (size_t)g * CPG_) * L_ + (size_t)half * 2048;

  float s = 0.f, ss = 0.f;
#pragma unroll
  for (int cc = 0; cc < 4; ++cc) {
#pragma unroll
    for (int i = 0; i < 2; ++i) {
      size_t e = base + (size_t)cc * L_ + i * 1024 + t * 4;
      float4 f = ldx4(x, e, f32);
      s += f.x + f.y + f.z + f.w;
      ss += f.x * f.x + f.y * f.y + f.z * f.z + f.w * f.w;
    }
  }
#pragma unroll
  for (int m = 32; m >= 1; m >>= 1) {
    s += __shfl_xor(s, m, 64);
    ss += __shfl_xor(ss, m, 64);
  }
  __shared__ float red[4][2];
  int wv = t >> 6;
  if ((t & 63) == 0) { red[wv][0] = s; red[wv][1] = ss; }
  __syncthreads();
  if (t == 0) {
    float ts = red[0][0] + red[1][0] + red[2][0] + red[3][0];
    float tss = red[0][1] + red[1][1] + red[2][1] + red[3][1];
    gpart[(b * 32 + g) * 2 + half] = make_float2(ts, tss);
  }
}

// ---------------------------------------------------------------- QKV GEMM (MFMA, gn inline)
// GN finalize in-block from gpart partials (cheap, redundant per block).
__global__ __launch_bounds__(256) void qkv_kernel(const ushort* __restrict__ wq_b,
                                                  const void* __restrict__ x,
                                                  const float2* __restrict__ gpart,
                                                  const void* __restrict__ gm,
                                                  const void* __restrict__ bt,
                                                  ushort* __restrict__ Qt,
                                                  ushort* __restrict__ Kt,
                                                  ushort* __restrict__ Vb) {
  bool f32 = detect_fast((const ushort*)x);
  __shared__ alignas(16) ushort Hs[64][136];
  __shared__ alignas(16) float Ls[64][69];
  __shared__ float2 abs_s[128];

  int lx = blockIdx.x, oz = blockIdx.y, b = blockIdx.z;
  int t = threadIdx.x;
  int w = t >> 6, lane = t & 63, l16 = lane & 15, q = lane >> 4, q8 = q * 8;

  if (t < 64) {
#pragma unroll
    for (int k = 0; k < 2; ++k) {
      int c = 2 * t + k;
      int g = c >> 2;
      float2 p0 = gpart[(b * 32 + g) * 2];
      float2 p1 = gpart[(b * 32 + g) * 2 + 1];
      float mu = (p0.x + p1.x) * (1.0f / 16384.0f);
      float var = (p0.y + p1.y) * (1.0f / 16384.0f) - mu * mu;
      float rs = rsqrtf(var + EPS_);
      float ga = f32 ? ((const float*)gm)[c] : bu2f(((const ushort*)gm)[c]);
      float be = f32 ? ((const float*)bt)[c] : bu2f(((const ushort*)bt)[c]);
      abs_s[c] = make_float2(ga * rs, be - mu * ga * rs);
    }
  }
  __syncthreads();

  {
    int u = t & 63, lh = (t >> 6) * 16;
    int c0 = 2 * u;
    float2 ab0 = abs_s[c0];
    float2 ab1 = abs_s[c0 + 1];
    size_t xo = ((size_t)b * C_ + c0) * L_ + (size_t)lx * 64 + lh;
#pragma unroll
    for (int j = 0; j < 4; ++j) {
      float4 f0 = ldx4(x, xo + j * 4, f32);
      float4 f1 = ldx4(x, xo + L_ + j * 4, f32);
      float n0[4] = {f0.x * ab0.x + ab0.y, f0.y * ab0.x + ab0.y,
                     f0.z * ab0.x + ab0.y, f0.w * ab0.x + ab0.y};
      float n1[4] = {f1.x * ab1.x + ab1.y, f1.y * ab1.x + ab1.y,
                     f1.z * ab1.x + ab1.y, f1.w * ab1.x + ab1.y};
#pragma unroll
      for (int k = 0; k < 4; ++k)
        *(unsigned int*)&Hs[lh + j * 4 + k][c0] = pkbf(n0[k], n1[k]);
    }
  }
  __syncthreads();

  for (int j = 0; j < 2; ++j) {
    int oy = oz * 2 + j;
    const ushort* wg = wq_b + (size_t)(oy * 64 + w * 16 + l16) * C_;

    f32x4 acc[4] = {{0.f, 0.f, 0.f, 0.f}, {0.f, 0.f, 0.f, 0.f},
                    {0.f, 0.f, 0.f, 0.f}, {0.f, 0.f, 0.f, 0.f}};
#pragma unroll
    for (int kc = 0; kc < 4; ++kc) {
      bf16x8 aw = *(const bf16x8*)(wg + kc * 32 + q8);
#pragma unroll
      for (int nb = 0; nb < 4; ++nb) {
        bf16x8 bh = *(const bf16x8*)&Hs[nb * 16 + l16][kc * 32 + q8];
        acc[nb] = __builtin_amdgcn_mfma_f32_16x16x32_bf16(aw, bh, acc[nb], 0, 0, 0);
      }
    }
    __syncthreads();
#pragma unroll
    for (int nb = 0; nb < 4; ++nb)
#pragma unroll
      for (int r = 0; r < 4; ++r)
        Ls[nb * 16 + l16][w * 16 + 4 * q + r] = acc[nb][r];
    __syncthreads();

#pragma unroll
    for (int hhalf = 0; hhalf < 2; ++hhalf) {
      int hh = oy * 2 + hhalf;
      int type = hh % 3, head = hh / 3;
      size_t bh = (size_t)b * H_ + head;
      if (type == 2) {
        int c_loc = t >> 3, l8 = (t & 7) * 8;
        float v[8];
#pragma unroll
        for (int jj = 0; jj < 8; ++jj) v[jj] = Ls[l8 + jj][hhalf * 32 + c_loc];
        uint4 u;
        u.x = pkhf(v[0], v[1]);
        u.y = pkhf(v[2], v[3]);
        u.z = pkhf(v[4], v[5]);
        u.w = pkhf(v[6], v[7]);
        *(uint4*)(Vb + (bh * 32 + c_loc) * L_ + (size_t)lx * 64 + l8) = u;
      } else {
        ushort* dst = type ? Kt : Qt;
        int l = t >> 2, seg = (t & 3) * 8;
        const float* src = &Ls[l][hhalf * 32 + seg];
        uint4 u;
        u.x = pkbf(src[0] * QKSCALE_, src[1] * QKSCALE_);
        u.y = pkbf(src[2] * QKSCALE_, src[3] * QKSCALE_);
        u.z = pkbf(src[4] * QKSCALE_, src[5] * QKSCALE_);
        u.w = pkbf(src[6] * QKSCALE_, src[7] * QKSCALE_);
        *(uint4*)(dst + ((bh * L_) + lx * 64 + l) * 32 + seg) = u;
      }
    }
  }
}

// ---------------------------------------------------------------- MFMA flash attention v6
// R3 wave mapping + counted-vmcnt 4-slot ring.
// Per iter: s_waitcnt vmcnt(4) (tile it done; it+1, it+2 in flight) -> raw s_barrier
// -> issue DMA for tile it+3 into slot (it+3)&3 (held tile it-1, dead: all waves
// passed this barrier after computing it-1) -> compute tile it from slot it&3.
__global__ __launch_bounds__(512) void attn_kernel(const ushort* __restrict__ Qt,
                                                   const ushort* __restrict__ Kt,
                                                   const ushort* __restrict__ Vb,
                                                   ushort* __restrict__ ot) {
  // K slots: [slot*8192, +8192) ; V slots: [32768 + slot*8192, +8192)
  // epilogue overlay: Osh [8][32][33] f32 = 33792B ; Lp [4][128] f32 @ 33792
  __shared__ alignas(16) char smem[65536];

  int t = threadIdx.x;
  int w = t >> 6, lane = t & 63, l31 = lane & 31, hi = lane >> 5;
  int qt = w & 3, sh = w >> 2;
  int tq0 = blockIdx.x * 128;
  int bh = blockIdx.y;
  int b = bh >> 2, head = bh & 3;
  const ushort* Qg = Qt + ((size_t)bh * L_ + tq0) * 32;
  const ushort* Kg = Kt + (size_t)bh * L_ * 32;
  const ushort* Vg = Vb + (size_t)bh * 32 * L_;

  // staging sources (pre-swizzled so linear DMA dest yields swizzled LDS)
  int rd = t >> 2, pd = t & 3;
  int kcsem = (pd - rd) & 3;
  const ushort* ksrc = Kg + (size_t)rd * 32 + kcsem * 8;
  int vr = t >> 4, vp = t & 15;
  int vcsem = (vp & 8) | ((vp & 7) ^ (vr & 7));
  const ushort* vsrc = Vg + (size_t)vr * L_ + vcsem * 8;

  // Q fragments (B operand): lane holds Q[q=qt*32+l31][k = 8*hi + j] (+16 for 2nd K-half)
  const ushort* qbase = Qg + (size_t)(qt * 32 + l31) * 32;
  bf16x8 qB0 = *(const bf16x8*)(qbase + 8 * hi);
  bf16x8 qB1 = *(const bf16x8*)(qbase + 16 + 8 * hi);

  const f16x2 one2 = {(_Float16)1.0f, (_Float16)1.0f};

  // prologue: issue tiles 0..2 (6 loads/wave in flight)
#pragma unroll
  for (int s = 0; s < 3; ++s) {
    gload16(ksrc, smem + s * 8192 + (size_t)t * 16);
    gload16(vsrc, smem + 32768 + s * 8192 + (size_t)t * 16);
    ksrc += 4096;
    vsrc += 128;
  }

  f32x16 aO = {0.f};
  float lsum = 0.f;

  for (int it = 0; it < 32; ++it) {
    int rem = 31 - it;
    if (rem >= 2) {
      asm volatile("s_waitcnt vmcnt(4)" ::: "memory");
    } else if (rem == 1) {
      asm volatile("s_waitcnt vmcnt(2)" ::: "memory");
    } else {
      asm volatile("s_waitcnt vmcnt(0)" ::: "memory");
    }
    __builtin_amdgcn_sched_barrier(0);
    __builtin_amdgcn_s_barrier();
    __builtin_amdgcn_sched_barrier(0);

    if (it < 29) {
      char* kd = smem + ((it + 3) & 3) * 8192;
      char* vd = smem + 32768 + ((it + 3) & 3) * 8192;
      gload16(ksrc, kd + (size_t)t * 16);
      gload16(vsrc, vd + (size_t)t * 16);
      ksrc += 4096;
      vsrc += 128;
    }

    const ushort* kc = (const ushort*)(smem + (it & 3) * 8192);
    const ushort* vc = (const ushort*)(smem + 32768 + (it & 3) * 8192);

#pragma unroll
    for (int st = 0; st < 2; ++st) {
      int s0 = 64 * sh + 32 * st;
      const ushort* krow = kc + (size_t)(s0 + l31) * 32;
      bf16x8 aK0 = *(const bf16x8*)(krow + ((hi + l31) & 3) * 8);
      bf16x8 aK1 = *(const bf16x8*)(krow + ((2 + hi + l31) & 3) * 8);
      f32x16 zz = {0.f};
      f32x16 sf;
      __builtin_amdgcn_s_setprio(1);
      sf = __builtin_amdgcn_mfma_f32_32x32x16_bf16(aK0, qB0, zz, 0, 0, 0);
      sf = __builtin_amdgcn_mfma_f32_32x32x16_bf16(aK1, qB1, sf, 0, 0, 0);
      __builtin_amdgcn_s_setprio(0);

#pragma unroll
      for (int sb = 0; sb < 2; ++sb) {
        int sblk = 4 * sh + 2 * st + sb;
        // V fragment (A operand): V[c=l31][s = sblk*16 + 8*hi + j]
        int kci = 2 * sblk + hi;
        int vpos = (kci & 8) | ((kci & 7) ^ (l31 & 7));
        f16x8 vf = *(const f16x8*)(vc + (size_t)l31 * 128 + vpos * 8);

        float p0 = EXP2F(sf[8 * sb + 0]);
        float p1 = EXP2F(sf[8 * sb + 1]);
        float p2 = EXP2F(sf[8 * sb + 2]);
        float p3 = EXP2F(sf[8 * sb + 3]);
        float p4 = EXP2F(sf[8 * sb + 4]);
        float p5 = EXP2F(sf[8 * sb + 5]);
        float p6 = EXP2F(sf[8 * sb + 6]);
        float p7 = EXP2F(sf[8 * sb + 7]);
        f16x2 cA0 = pkhf2(p0, p1), cA1 = pkhf2(p2, p3);
        f16x2 cB0 = pkhf2(p4, p5), cB1 = pkhf2(p6, p7);
        lsum = __builtin_amdgcn_fdot2(cA0, one2, lsum, false);
        lsum = __builtin_amdgcn_fdot2(cA1, one2, lsum, false);
        lsum = __builtin_amdgcn_fdot2(cB0, one2, lsum, false);
        lsum = __builtin_amdgcn_fdot2(cB1, one2, lsum, false);

        // B-fragment repack: (w0,w2) = swap(cA0, cB0); (w1,w3) = swap(cA1, cB1)
        u32x2 r0 = __builtin_amdgcn_permlane32_swap(
            __builtin_bit_cast(unsigned int, cA0),
            __builtin_bit_cast(unsigned int, cB0), false, false);
        u32x2 r1 = __builtin_amdgcn_permlane32_swap(
            __builtin_bit_cast(unsigned int, cA1),
            __builtin_bit_cast(unsigned int, cB1), false, false);
        u32x4 pw = {r0.x, r1.x, r0.y, r1.y};
        f16x8 pf = __builtin_bit_cast(f16x8, pw);

        __builtin_amdgcn_s_setprio(1);
        aO = __builtin_amdgcn_mfma_f32_32x32x16_f16(vf, pf, aO, 0, 0, 0);
        __builtin_amdgcn_s_setprio(0);
      }
    }
  }
  __syncthreads();

  // ---- epilogue: write partials (padded rows: bank = (l31 + c) % 32, conflict-free)
  float* Osh = (float*)smem;                // [slot=sh*4+qt][q=32][c=33pad]
  float* Lp = (float*)(smem + 33792);       // [sh*2+hi][128]
  {
    float* ob = Osh + (size_t)(sh * 4 + qt) * (32 * 33) + (size_t)l31 * 33;
#pragma unroll
    for (int reg = 0; reg < 16; ++reg) {
      int R = (reg & 3) + 8 * (reg >> 2) + 4 * hi;
      ob[R] = aO[reg];
    }
    Lp[(sh * 2 + hi) * 128 + qt * 32 + l31] = lsum;
  }
  __syncthreads();

  // combine s-halves + hi-halves, normalize, pack bf16, coalesced store
  {
    int qloc = t >> 2, c0 = (t & 3) * 8;
    int qt2 = qloc >> 5, q31 = qloc & 31;
    float lt = Lp[qloc] + Lp[128 + qloc] + Lp[256 + qloc] + Lp[384 + qloc];
    float inv = 1.0f / lt;
    const float* o0 = Osh + (size_t)qt2 * (32 * 33) + (size_t)q31 * 33 + c0;
    const float* o1 = o0 + 4 * (32 * 33);
    float o[8];
#pragma unroll
    for (int jj = 0; jj < 8; ++jj) o[jj] = (o0[jj] + o1[jj]) * inv;
    uint4 u;
    u.x = pkbf(o[0], o[1]);
    u.y = pkbf(o[2], o[3]);
    u.z = pkbf(o[4], o[5]);
    u.w = pkbf(o[6], o[7]);
    *(uint4*)(ot + ((size_t)b * L_ + tq0 + qloc) * C_ + head * 32 + c0) = u;
  }
}

// ---------------------------------------------------------------- Proj + bias + residual
__global__ __launch_bounds__(256) void proj_kernel(const ushort* __restrict__ wp_b,
                                                   const float* __restrict__ bias,
                                                   const void* __restrict__ x,
                                                   const ushort* __restrict__ ot,
                                                   void* __restrict__ out) {
  bool f32 = detect_fast((const ushort*)x);
  __shared__ alignas(16) float Ls[64][37];

  int lx = blockIdx.x, oy = blockIdx.y, b = blockIdx.z;
  int t = threadIdx.x;
  int w = t >> 6, lane = t & 63, l16 = lane & 15, q = lane >> 4, q8 = q * 8;

  const ushort* wg = wp_b + (size_t)(oy * 64 + w * 16 + l16) * C_;
  const ushort* og = ot + ((size_t)b * L_ + (size_t)lx * 32) * C_;

  f32x4 acc[2] = {{0.f, 0.f, 0.f, 0.f}, {0.f, 0.f, 0.f, 0.f}};
#pragma unroll
  for (int kc = 0; kc < 4; ++kc) {
    bf16x8 aw = *(const bf16x8*)(wg + kc * 32 + q8);
#pragma unroll
    for (int nb = 0; nb < 2; ++nb) {
      bf16x8 bo = *(const bf16x8*)(og + (size_t)(nb * 16 + l16) * C_ + kc * 32 + q8);
      acc[nb] = __builtin_amdgcn_mfma_f32_16x16x32_bf16(aw, bo, acc[nb], 0, 0, 0);
    }
  }
#pragma unroll
  for (int nb = 0; nb < 2; ++nb)
#pragma unroll
    for (int r = 0; r < 4; ++r)
      Ls[w * 16 + 4 * q + r][nb * 16 + l16] = acc[nb][r];
  __syncthreads();

  {
    int o_loc = t >> 2, ls0 = (t & 3) * 8;
    float bv = bias[oy * 64 + o_loc];
    size_t off = ((size_t)b * C_ + oy * 64 + o_loc) * L_ + (size_t)lx * 32 + ls0;
#pragma unroll
    for (int jj = 0; jj < 2; ++jj) {
      float4 xf = ldx4(x, off + jj * 4, f32);
      const float* sp = &Ls[o_loc][ls0 + jj * 4];
      float4 r = make_float4(sp[0] + bv + xf.x, sp[1] + bv + xf.y,
                             sp[2] + bv + xf.z, sp[3] + bv + xf.w);
      if (f32) {
        *(float4*)((float*)out + off + jj * 4) = r;
      } else {
        *(ushort4*)((ushort*)out + off + jj * 4) =
            make_ushort4(f2bu(r.x), f2bu(r.y), f2bu(r.z), f2bu(r.w));
      }
    }
  }
}

// ---------------------------------------------------------------- launch
extern "C" void kernel_launch(void* const* d_in, const int* in_sizes, int n_in,
                              void* d_out, int out_size, void* d_ws, size_t ws_size,
                              hipStream_t stream) {
  const void* x      = d_in[0];
  const void* w_qkv  = d_in[1];
  const void* w_proj = d_in[2];
  const void* b_proj = d_in[3];
  const void* gamma  = d_in[4];
  const void* beta   = d_in[5];

  char* wsb = (char*)d_ws;
  ushort* wq_b  = (ushort*)(wsb + 0);
  ushort* wp_b  = (ushort*)(wsb + 98304);
  float*  bp_f  = (float*)(wsb + 131072);
  float2* gpart = (float2*)(wsb + 131584);
  ushort* Qt    = (ushort*)(wsb + 8388608);
  ushort* Kt    = (ushort*)(wsb + 12582912);
  ushort* Vb    = (ushort*)(wsb + 16777216);  // fp16
  ushort* ot    = (ushort*)(wsb + 20971520);

  gn_stats<<<dim3(289), dim3(256), 0, stream>>>(x, w_qkv, w_proj, b_proj,
                                                wq_b, wp_b, bp_f, gpart);
  qkv_kernel<<<dim3(L_ / 64, 3, B_), dim3(256), 0, stream>>>(wq_b, x, gpart, gamma, beta,
                                                             Qt, Kt, Vb);
  attn_kernel<<<dim3(L_ / 128, B_ * H_), dim3(512), 0, stream>>>(Qt, Kt, Vb, ot);
  proj_kernel<<<dim3(L_ / 32, C_ / 64, B_), dim3(256), 0, stream>>>(wp_b, bp_f, x, ot, d_out);
}